// Round 1
// baseline (515.319 us; speedup 1.0000x reference)
//
#include <hip/hip_runtime.h>
#include <hip/hip_bf16.h>
#include <math.h>

#define BB 16
#define LL 200
#define HH 128
#define NHH 2
#define DD 64
#define NEGF -4294967295.0f
#define SQRTH 11.313708498984761f

__device__ __forceinline__ float waveSum(float v) {
    v += __shfl_xor(v, 1, 64);
    v += __shfl_xor(v, 2, 64);
    v += __shfl_xor(v, 4, 64);
    v += __shfl_xor(v, 8, 64);
    v += __shfl_xor(v, 16, 64);
    v += __shfl_xor(v, 32, 64);
    return v;
}

__device__ __forceinline__ float waveMax(float v) {
    v = fmaxf(v, __shfl_xor(v, 1, 64));
    v = fmaxf(v, __shfl_xor(v, 2, 64));
    v = fmaxf(v, __shfl_xor(v, 4, 64));
    v = fmaxf(v, __shfl_xor(v, 8, 64));
    v = fmaxf(v, __shfl_xor(v, 16, 64));
    v = fmaxf(v, __shfl_xor(v, 32, 64));
    return v;
}

// seqs[b,l,:] = item_emb[log_seqs[b,l]] * sqrt(H) * keep
__global__ void k_embed(const int* __restrict__ log_seqs,
                        const float* __restrict__ item_emb,
                        float* __restrict__ seqs) {
    int row = blockIdx.x;          // b*LL + l
    int t = threadIdx.x;           // 0..127
    int id = log_seqs[row];
    float v = (id == 0) ? 0.0f : item_emb[id * HH + t] * SQRTH;
    seqs[row * HH + t] = v;
}

// Q/K/V = seqs @ W^T + b   (one block per row, 384 threads: 128 per matrix)
__global__ void k_qkv(const float* __restrict__ seqs,
                      const float* __restrict__ Wq, const float* __restrict__ bq,
                      const float* __restrict__ Wk, const float* __restrict__ bk,
                      const float* __restrict__ Wv, const float* __restrict__ bv,
                      float* __restrict__ Q, float* __restrict__ K, float* __restrict__ V) {
    __shared__ float srow[HH];
    int row = blockIdx.x;
    int t = threadIdx.x;
    if (t < HH) srow[t] = seqs[row * HH + t];
    __syncthreads();
    int which = t >> 7;            // 0,1,2
    int col = t & 127;
    const float* W = (which == 0) ? Wq : (which == 1) ? Wk : Wv;
    const float* bb = (which == 0) ? bq : (which == 1) ? bk : bv;
    float acc = bb[col];
    const float4* wr = (const float4*)(W + col * HH);
    const float4* sr = (const float4*)srow;
#pragma unroll
    for (int k4 = 0; k4 < HH / 4; ++k4) {
        float4 w = wr[k4];
        float4 s = sr[k4];
        acc += s.x * w.x + s.y * w.y + s.z * w.z + s.w * w.w;
    }
    float* O = (which == 0) ? Q : (which == 1) ? K : V;
    O[row * HH + col] = acc;
}

// scores + softmax fused: one block per (b,h,q), one thread per k
__global__ void k_scores(const float* __restrict__ Q, const float* __restrict__ K,
                         const float* __restrict__ posK, const float* __restrict__ timeK,
                         const int* __restrict__ tm, const int* __restrict__ log_seqs,
                         float* __restrict__ A) {
    int idx = blockIdx.x;          // (b*NHH + h)*LL + q
    int q = idx % LL;
    int bh = idx / LL;
    int h = bh & 1;
    int b = bh >> 1;
    __shared__ float qrow[DD];
    __shared__ float red[4];
    int t = threadIdx.x;           // 256 threads
    if (t < DD) qrow[t] = Q[(b * LL + q) * HH + h * DD + t];
    __syncthreads();
    float s = -INFINITY;
    if (t < LL) {
        bool masked = (t > q) || (log_seqs[b * LL + t] == 0);
        if (masked) {
            s = NEGF;
        } else {
            int tt = tm[(b * LL + q) * LL + t];
            const float4* kp = (const float4*)(K + (b * LL + t) * HH + h * DD);
            const float4* pp = (const float4*)(posK + t * HH + h * DD);
            const float4* tp = (const float4*)(timeK + tt * HH + h * DD);
            const float4* qp = (const float4*)qrow;
            float acc = 0.0f;
#pragma unroll
            for (int d4 = 0; d4 < DD / 4; ++d4) {
                float4 kv = kp[d4], pv = pp[d4], tv = tp[d4], qv = qp[d4];
                acc += qv.x * (kv.x + pv.x + tv.x);
                acc += qv.y * (kv.y + pv.y + tv.y);
                acc += qv.z * (kv.z + pv.z + tv.z);
                acc += qv.w * (kv.w + pv.w + tv.w);
            }
            s = acc * 0.125f;      // / sqrt(64)
        }
    }
    // block max (256 threads = 4 waves)
    float m = waveMax(s);
    if ((t & 63) == 0) red[t >> 6] = m;
    __syncthreads();
    m = fmaxf(fmaxf(red[0], red[1]), fmaxf(red[2], red[3]));
    float e = (t < LL) ? expf(s - m) : 0.0f;
    __syncthreads();               // protect red before reuse
    float ssum = waveSum(e);
    if ((t & 63) == 0) red[t >> 6] = ssum;
    __syncthreads();
    float denom = red[0] + red[1] + red[2] + red[3];
    if (t < LL) A[idx * LL + t] = e / denom;
}

// out[b,q,:] = sum_k A*(V+posV+timeV); then seqs = LN(seqs + out)
__global__ void k_attnout_ln(const float* __restrict__ A, const float* __restrict__ V,
                             const float* __restrict__ posV, const float* __restrict__ timeV,
                             const int* __restrict__ tm,
                             float* __restrict__ seqs,
                             const float* __restrict__ g, const float* __restrict__ beta) {
    int row = blockIdx.x;          // b*LL + q
    int b = row / LL;
    int q = row % LL;
    int t = threadIdx.x;           // 128 threads; h = t>>6
    __shared__ float sA[NHH][LL];
    __shared__ int sT[LL];
    __shared__ float red[2];
    for (int k = t; k < LL; k += HH) {
        sA[0][k] = A[((b * 2 + 0) * LL + q) * LL + k];
        sA[1][k] = A[((b * 2 + 1) * LL + q) * LL + k];
        sT[k] = tm[row * LL + k];
    }
    __syncthreads();
    int h = t >> 6;
    float acc = 0.0f;
    for (int k = 0; k < LL; ++k) {
        float a = sA[h][k];
        int tt = sT[k];
        acc += a * (V[(b * LL + k) * HH + t] + posV[k * HH + t] + timeV[tt * HH + t]);
    }
    float x = seqs[row * HH + t] + acc;
    // LayerNorm over 128
    float m = waveSum(x);
    if ((t & 63) == 0) red[t >> 6] = m;
    __syncthreads();
    m = (red[0] + red[1]) * (1.0f / HH);
    float d = x - m;
    __syncthreads();
    float v2 = waveSum(d * d);
    if ((t & 63) == 0) red[t >> 6] = v2;
    __syncthreads();
    float var = (red[0] + red[1]) * (1.0f / HH);
    seqs[row * HH + t] = d * rsqrtf(var + 1e-8f) * g[t] + beta[t];
}

// h1 = relu(seqs @ W1^T + b1)
__global__ void k_ffn1(const float* __restrict__ seqs, const float* __restrict__ W1,
                       const float* __restrict__ b1, float* __restrict__ h1) {
    __shared__ float srow[HH];
    int row = blockIdx.x;
    int t = threadIdx.x;
    srow[t] = seqs[row * HH + t];
    __syncthreads();
    float acc = b1[t];
    const float4* wr = (const float4*)(W1 + t * HH);
    const float4* sr = (const float4*)srow;
#pragma unroll
    for (int k4 = 0; k4 < HH / 4; ++k4) {
        float4 w = wr[k4];
        float4 s = sr[k4];
        acc += s.x * w.x + s.y * w.y + s.z * w.z + s.w * w.w;
    }
    h1[row * HH + t] = fmaxf(acc, 0.0f);
}

// seqs = LN(seqs + h1 @ W2^T + b2) * keep
__global__ void k_ffn2_ln(const float* __restrict__ h1, const float* __restrict__ W2,
                          const float* __restrict__ b2, float* __restrict__ seqs,
                          const float* __restrict__ g, const float* __restrict__ beta,
                          const int* __restrict__ log_seqs) {
    __shared__ float srow[HH];
    __shared__ float red[2];
    int row = blockIdx.x;
    int t = threadIdx.x;
    srow[t] = h1[row * HH + t];
    __syncthreads();
    float acc = b2[t];
    const float4* wr = (const float4*)(W2 + t * HH);
    const float4* sr = (const float4*)srow;
#pragma unroll
    for (int k4 = 0; k4 < HH / 4; ++k4) {
        float4 w = wr[k4];
        float4 s = sr[k4];
        acc += s.x * w.x + s.y * w.y + s.z * w.z + s.w * w.w;
    }
    float x = seqs[row * HH + t] + acc;
    float m = waveSum(x);
    if ((t & 63) == 0) red[t >> 6] = m;
    __syncthreads();
    m = (red[0] + red[1]) * (1.0f / HH);
    float d = x - m;
    __syncthreads();
    float v2 = waveSum(d * d);
    if ((t & 63) == 0) red[t >> 6] = v2;
    __syncthreads();
    float var = (red[0] + red[1]) * (1.0f / HH);
    float y = d * rsqrtf(var + 1e-8f) * g[t] + beta[t];
    float keep = (log_seqs[row] != 0) ? 1.0f : 0.0f;
    seqs[row * HH + t] = y * keep;
}

// log_feats = LN(seqs, lnf); pos/neg logits via dot with item_emb rows
__global__ void k_final(const float* __restrict__ seqs,
                        const float* __restrict__ lnf_g, const float* __restrict__ lnf_b,
                        const float* __restrict__ item_emb,
                        const int* __restrict__ pos_seqs, const int* __restrict__ neg_seqs,
                        float* __restrict__ out) {
    __shared__ float red[2];
    int row = blockIdx.x;          // b*LL + l
    int t = threadIdx.x;           // 128
    float x = seqs[row * HH + t];
    float m = waveSum(x);
    if ((t & 63) == 0) red[t >> 6] = m;
    __syncthreads();
    m = (red[0] + red[1]) * (1.0f / HH);
    float d = x - m;
    __syncthreads();
    float v2 = waveSum(d * d);
    if ((t & 63) == 0) red[t >> 6] = v2;
    __syncthreads();
    float var = (red[0] + red[1]) * (1.0f / HH);
    float lf = d * rsqrtf(var + 1e-8f) * lnf_g[t] + lnf_b[t];
    int pid = pos_seqs[row];
    int nid = neg_seqs[row];
    float pp = lf * item_emb[pid * HH + t];
    float nn = lf * item_emb[nid * HH + t];
    __syncthreads();
    float ps = waveSum(pp);
    if ((t & 63) == 0) red[t >> 6] = ps;
    __syncthreads();
    float ptot = red[0] + red[1];
    __syncthreads();
    float ns = waveSum(nn);
    if ((t & 63) == 0) red[t >> 6] = ns;
    __syncthreads();
    float ntot = red[0] + red[1];
    if (t == 0) {
        out[row] = ptot;               // pos_logits (B,L)
        out[BB * LL + row] = ntot;     // neg_logits (B,L)
    }
}

extern "C" void kernel_launch(void* const* d_in, const int* in_sizes, int n_in,
                              void* d_out, int out_size, void* d_ws, size_t ws_size,
                              hipStream_t stream) {
    const int* log_seqs = (const int*)d_in[1];
    const int* tm       = (const int*)d_in[2];
    const int* pos_seqs = (const int*)d_in[3];
    const int* neg_seqs = (const int*)d_in[4];
    const float* item_emb = (const float*)d_in[5];
    const float* posK   = (const float*)d_in[6];
    const float* posV   = (const float*)d_in[7];
    const float* timeK  = (const float*)d_in[8];
    const float* timeV  = (const float*)d_in[9];
    const float* Wq = (const float*)d_in[10];
    const float* bq = (const float*)d_in[11];
    const float* Wk = (const float*)d_in[12];
    const float* bk = (const float*)d_in[13];
    const float* Wv = (const float*)d_in[14];
    const float* bv = (const float*)d_in[15];
    const float* ln1_g = (const float*)d_in[16];
    const float* ln1_b = (const float*)d_in[17];
    const float* W1 = (const float*)d_in[18];
    const float* b1 = (const float*)d_in[19];
    const float* W2 = (const float*)d_in[20];
    const float* b2 = (const float*)d_in[21];
    const float* ln2_g = (const float*)d_in[22];
    const float* ln2_b = (const float*)d_in[23];
    const float* lnf_g = (const float*)d_in[24];
    const float* lnf_b = (const float*)d_in[25];

    float* ws   = (float*)d_ws;
    float* seqs = ws;                    // 409600
    float* Qb   = seqs + 409600;
    float* Kb   = Qb + 409600;
    float* Vb   = Kb + 409600;
    float* h1   = Vb + 409600;
    float* Ab   = h1 + 409600;           // 2,560,000

    k_embed<<<BB * LL, HH, 0, stream>>>(log_seqs, item_emb, seqs);
    for (int i = 0; i < NHH; ++i) {      // NB == 2 blocks
        k_qkv<<<BB * LL, 3 * HH, 0, stream>>>(seqs,
            Wq + i * HH * HH, bq + i * HH,
            Wk + i * HH * HH, bk + i * HH,
            Wv + i * HH * HH, bv + i * HH, Qb, Kb, Vb);
        k_scores<<<BB * NHH * LL, 256, 0, stream>>>(Qb, Kb, posK, timeK, tm, log_seqs, Ab);
        k_attnout_ln<<<BB * LL, HH, 0, stream>>>(Ab, Vb, posV, timeV, tm, seqs,
                                                 ln1_g + i * HH, ln1_b + i * HH);
        k_ffn1<<<BB * LL, HH, 0, stream>>>(seqs, W1 + i * HH * HH, b1 + i * HH, h1);
        k_ffn2_ln<<<BB * LL, HH, 0, stream>>>(h1, W2 + i * HH * HH, b2 + i * HH, seqs,
                                              ln2_g + i * HH, ln2_b + i * HH, log_seqs);
    }
    k_final<<<BB * LL, HH, 0, stream>>>(seqs, lnf_g, lnf_b, item_emb,
                                        pos_seqs, neg_seqs, (float*)d_out);
}

// Round 2
// 255.068 us; speedup vs baseline: 2.0203x; 2.0203x over previous
//
#include <hip/hip_runtime.h>
#include <hip/hip_bf16.h>
#include <math.h>

#define BB 16
#define LL 200
#define HH 128
#define DD 64
#define QT 16
#define NQT 13          // ceil(200/16)
#define NEGF -4294967295.0f
#define SQRTH 11.313708498984761f

__device__ __forceinline__ float waveSum(float v) {
    v += __shfl_xor(v, 1, 64);
    v += __shfl_xor(v, 2, 64);
    v += __shfl_xor(v, 4, 64);
    v += __shfl_xor(v, 8, 64);
    v += __shfl_xor(v, 16, 64);
    v += __shfl_xor(v, 32, 64);
    return v;
}

// ---------------- embed ----------------
__global__ void k_embed(const int* __restrict__ log_seqs,
                        const float* __restrict__ item_emb,
                        float* __restrict__ seqs) {
    int row = blockIdx.x;
    int t = threadIdx.x;
    int id = log_seqs[row];
    float v = (id == 0) ? 0.0f : item_emb[id * HH + t] * SQRTH;
    seqs[row * HH + t] = v;
}

// ---------------- QKV projection, 16 rows/block ----------------
// Q = seqs@Wq^T+bq ; Kp = seqs@Wk^T+bk+posK[l] ; Vp = seqs@Wv^T+bv+posV[l]
__global__ __launch_bounds__(256) void k_qkv_t(const float* __restrict__ seqs,
    const float* __restrict__ Wq, const float* __restrict__ bq,
    const float* __restrict__ Wk, const float* __restrict__ bk,
    const float* __restrict__ Wv, const float* __restrict__ bv,
    const float* __restrict__ posK, const float* __restrict__ posV,
    float* __restrict__ Q, float* __restrict__ Kp, float* __restrict__ Vp) {
    __shared__ float s_lds[16][HH];
    int r0g = blockIdx.x * 16;
    int t = threadIdx.x;
    {
        const float4* src = (const float4*)(seqs + r0g * HH);
        float4* dst = (float4*)&s_lds[0][0];
        for (int x = t; x < 16 * HH / 4; x += 256) dst[x] = src[x];
    }
    __syncthreads();
    int c = t & 127, rg = t >> 7;
    int r0 = rg * 8;
    float aq[8], ak[8], av[8];
#pragma unroll
    for (int r = 0; r < 8; ++r) { aq[r] = 0.f; ak[r] = 0.f; av[r] = 0.f; }
    const float4* wq4 = (const float4*)(Wq + c * HH);
    const float4* wk4 = (const float4*)(Wk + c * HH);
    const float4* wv4 = (const float4*)(Wv + c * HH);
#pragma unroll 2
    for (int k4 = 0; k4 < HH / 4; ++k4) {
        float4 wq = wq4[k4], wk = wk4[k4], wv = wv4[k4];
#pragma unroll
        for (int r = 0; r < 8; ++r) {
            float4 s = *(const float4*)&s_lds[r0 + r][k4 * 4];
            aq[r] += s.x * wq.x + s.y * wq.y + s.z * wq.z + s.w * wq.w;
            ak[r] += s.x * wk.x + s.y * wk.y + s.z * wk.z + s.w * wk.w;
            av[r] += s.x * wv.x + s.y * wv.y + s.z * wv.z + s.w * wv.w;
        }
    }
#pragma unroll
    for (int r = 0; r < 8; ++r) {
        int row = r0g + r0 + r;
        int l = row % LL;
        Q[row * HH + c]  = aq[r] + bq[c];
        Kp[row * HH + c] = ak[r] + bk[c] + posK[l * HH + c];
        Vp[row * HH + c] = av[r] + bv[c] + posV[l * HH + c];
    }
}

// ---------------- projK[b,h,q,tt] = Q[b,q,h,:] . timeK[tt,h,:] ----------------
// grid = 32 bh * 7 qtiles(32) ; 256 threads, thread = tt
__global__ __launch_bounds__(256) void k_proj(const float* __restrict__ Q,
    const float* __restrict__ timeK, float* __restrict__ projK) {
    int bh = blockIdx.x / 7, qt = blockIdx.x % 7;
    int b = bh >> 1, h = bh & 1;
    int qlo = qt * 32;
    __shared__ float Qs[32][DD];
    int t = threadIdx.x;
    for (int x = t; x < 32 * DD / 4; x += 256) {
        int r = x >> 4, d4 = x & 15;
        int q = qlo + r;
        float4 v = make_float4(0.f, 0.f, 0.f, 0.f);
        if (q < LL) v = ((const float4*)(Q + (b * LL + q) * HH + h * DD))[d4];
        *(float4*)&Qs[r][d4 * 4] = v;
    }
    __syncthreads();
    int qmax = LL - qlo; if (qmax > 32) qmax = 32;
    for (int tt = t; tt < 257; tt += 256) {
        float4 kr[16];
        const float4* tk4 = (const float4*)(timeK + tt * HH + h * DD);
#pragma unroll
        for (int d4 = 0; d4 < 16; ++d4) kr[d4] = tk4[d4];
        for (int r = 0; r < qmax; ++r) {
            float acc = 0.f;
#pragma unroll
            for (int d4 = 0; d4 < 16; ++d4) {
                float4 qv = *(const float4*)&Qs[r][d4 * 4];
                acc += qv.x * kr[d4].x + qv.y * kr[d4].y + qv.z * kr[d4].z + qv.w * kr[d4].w;
            }
            projK[(bh * LL + qlo + r) * 257 + tt] = acc;
        }
    }
}

// ---------------- fused scores + softmax + PV ----------------
// grid = 32 bh * 13 qtiles(16) ; 256 threads: tq = t>>4 (row), tk0 = t&15
__global__ __launch_bounds__(256) void k_attn(
    const float* __restrict__ Q, const float* __restrict__ Kp, const float* __restrict__ Vp,
    const float* __restrict__ projK, const float* __restrict__ timeV,
    const int* __restrict__ tm, const int* __restrict__ log_seqs,
    float* __restrict__ attnout) {
    int bh = blockIdx.x / NQT, qt = blockIdx.x % NQT;
    int b = bh >> 1, h = bh & 1;
    int qlo = qt * QT;
    __shared__ float Qs[QT][68];    // pad 68: conflict-free strided reads
    __shared__ float KV[64][68];
    __shared__ float S[QT][212];    // pad 212: conflict-free broadcast reads
    int t = threadIdx.x;
    int tq = t >> 4, tk0 = t & 15;
    int q = qlo + tq;
    int qhi = qlo + QT - 1; if (qhi > LL - 1) qhi = LL - 1;

    for (int x = t; x < QT * 16; x += 256) {
        int r = x >> 4, d4 = x & 15;
        int qq = qlo + r;
        float4 v = make_float4(0.f, 0.f, 0.f, 0.f);
        if (qq < LL) v = ((const float4*)(Q + (b * LL + qq) * HH + h * DD))[d4];
        *(float4*)&Qs[r][d4 * 4] = v;
    }
    for (int x = t; x < QT * LL; x += 256) S[x / LL][x % LL] = NEGF;
    __syncthreads();

    const int* tmrow = tm + (b * LL + q) * LL;
    const float* projrow = projK + (bh * LL + q) * 257;

    // phase 1: scores
    for (int kt = 0; kt * 64 <= qhi; ++kt) {
        int kbase = kt * 64;
        for (int x = t; x < 64 * 16; x += 256) {
            int i = x >> 4, d4 = x & 15;
            int k = kbase + i;
            if (k < LL) *(float4*)&KV[i][d4 * 4] =
                ((const float4*)(Kp + (b * LL + k) * HH + h * DD))[d4];
        }
        __syncthreads();
        if (q < LL) {
#pragma unroll
            for (int j = 0; j < 4; ++j) {
                int kk = tk0 + 16 * j;
                int k = kbase + kk;
                if (k < LL && k <= q && log_seqs[b * LL + k] != 0) {
                    float acc = 0.f;
#pragma unroll
                    for (int d4 = 0; d4 < 16; ++d4) {
                        float4 qv = *(const float4*)&Qs[tq][d4 * 4];
                        float4 kv = *(const float4*)&KV[kk][d4 * 4];
                        acc += qv.x * kv.x + qv.y * kv.y + qv.z * kv.z + qv.w * kv.w;
                    }
                    int tt = tmrow[k];
                    S[tq][k] = (acc + projrow[tt]) * 0.125f;
                }
            }
        }
        __syncthreads();
    }

    // phase 2: softmax over 200 (16 lanes per row)
    float mx = -INFINITY;
    bool allmask = false;
    if (q < LL) {
        for (int k = tk0; k < LL; k += 16) mx = fmaxf(mx, S[tq][k]);
        mx = fmaxf(mx, __shfl_xor(mx, 1, 64));
        mx = fmaxf(mx, __shfl_xor(mx, 2, 64));
        mx = fmaxf(mx, __shfl_xor(mx, 4, 64));
        mx = fmaxf(mx, __shfl_xor(mx, 8, 64));
        allmask = (mx == NEGF);
        float sum = 0.f;
        for (int k = tk0; k < LL; k += 16) {
            float e = expf(S[tq][k] - mx);
            S[tq][k] = e;
            sum += e;
        }
        sum += __shfl_xor(sum, 1, 64);
        sum += __shfl_xor(sum, 2, 64);
        sum += __shfl_xor(sum, 4, 64);
        sum += __shfl_xor(sum, 8, 64);
        float inv = 1.0f / sum;
        for (int k = tk0; k < LL; k += 16) S[tq][k] *= inv;
    }

    // phase 3: out[q, d] = sum_k A * (Vp[k,d] + timeV[tm[q,k], d])
    float4 acc = make_float4(0.f, 0.f, 0.f, 0.f);
    int klim = (q < LL) ? (allmask ? LL : q + 1) : 0;
    for (int kt = 0; kt < 4; ++kt) {
        int kbase = kt * 64;
        __syncthreads();
        for (int x = t; x < 64 * 16; x += 256) {
            int i = x >> 4, d4 = x & 15;
            int k = kbase + i;
            if (k < LL) *(float4*)&KV[i][d4 * 4] =
                ((const float4*)(Vp + (b * LL + k) * HH + h * DD))[d4];
        }
        __syncthreads();
        int kend = klim - kbase; if (kend > 64) kend = 64;
#pragma unroll 4
        for (int kk = 0; kk < kend; ++kk) {
            int k = kbase + kk;
            float a = S[tq][k];
            float4 vv = *(const float4*)&KV[kk][tk0 * 4];
            int tt = tmrow[k];
            float4 tv = *((const float4*)(timeV + tt * HH + h * DD) + tk0);
            acc.x += a * (vv.x + tv.x);
            acc.y += a * (vv.y + tv.y);
            acc.z += a * (vv.z + tv.z);
            acc.w += a * (vv.w + tv.w);
        }
    }
    if (q < LL)
        *(float4*)(attnout + (b * LL + q) * HH + h * DD + tk0 * 4) = acc;
}

// ---------------- residual add + LayerNorm (+ optional keep mask) ----------------
__global__ void k_add_ln(float* __restrict__ seqs, const float* __restrict__ delta,
                         const float* __restrict__ g, const float* __restrict__ beta,
                         const int* __restrict__ log_seqs, int keep) {
    __shared__ float red[2];
    int row = blockIdx.x;
    int t = threadIdx.x;
    float x = seqs[row * HH + t] + delta[row * HH + t];
    float m = waveSum(x);
    if ((t & 63) == 0) red[t >> 6] = m;
    __syncthreads();
    m = (red[0] + red[1]) * (1.0f / HH);
    float d = x - m;
    __syncthreads();
    float v2 = waveSum(d * d);
    if ((t & 63) == 0) red[t >> 6] = v2;
    __syncthreads();
    float var = (red[0] + red[1]) * (1.0f / HH);
    float y = d * rsqrtf(var + 1e-8f) * g[t] + beta[t];
    if (keep && log_seqs[row] == 0) y = 0.f;
    seqs[row * HH + t] = y;
}

// ---------------- fused FFN: delta = relu(seqs@W1^T+b1)@W2^T+b2 ----------------
__global__ __launch_bounds__(256) void k_ffn_t(const float* __restrict__ seqs,
    const float* __restrict__ W1, const float* __restrict__ b1,
    const float* __restrict__ W2, const float* __restrict__ b2,
    float* __restrict__ delta) {
    __shared__ float s_lds[16][HH];
    __shared__ float h_lds[16][HH];
    int r0g = blockIdx.x * 16;
    int t = threadIdx.x;
    {
        const float4* src = (const float4*)(seqs + r0g * HH);
        float4* dst = (float4*)&s_lds[0][0];
        for (int x = t; x < 16 * HH / 4; x += 256) dst[x] = src[x];
    }
    __syncthreads();
    int c = t & 127, rg = t >> 7;
    int r0 = rg * 8;
    float acc[8];
#pragma unroll
    for (int r = 0; r < 8; ++r) acc[r] = 0.f;
    const float4* w14 = (const float4*)(W1 + c * HH);
#pragma unroll 2
    for (int k4 = 0; k4 < HH / 4; ++k4) {
        float4 w = w14[k4];
#pragma unroll
        for (int r = 0; r < 8; ++r) {
            float4 s = *(const float4*)&s_lds[r0 + r][k4 * 4];
            acc[r] += s.x * w.x + s.y * w.y + s.z * w.z + s.w * w.w;
        }
    }
#pragma unroll
    for (int r = 0; r < 8; ++r) h_lds[r0 + r][c] = fmaxf(acc[r] + b1[c], 0.f);
    __syncthreads();
#pragma unroll
    for (int r = 0; r < 8; ++r) acc[r] = 0.f;
    const float4* w24 = (const float4*)(W2 + c * HH);
#pragma unroll 2
    for (int k4 = 0; k4 < HH / 4; ++k4) {
        float4 w = w24[k4];
#pragma unroll
        for (int r = 0; r < 8; ++r) {
            float4 s = *(const float4*)&h_lds[r0 + r][k4 * 4];
            acc[r] += s.x * w.x + s.y * w.y + s.z * w.z + s.w * w.w;
        }
    }
#pragma unroll
    for (int r = 0; r < 8; ++r)
        delta[(r0g + r0 + r) * HH + c] = acc[r] + b2[c];
}

// ---------------- final LN + logits ----------------
__global__ void k_final(const float* __restrict__ seqs,
                        const float* __restrict__ lnf_g, const float* __restrict__ lnf_b,
                        const float* __restrict__ item_emb,
                        const int* __restrict__ pos_seqs, const int* __restrict__ neg_seqs,
                        float* __restrict__ out) {
    __shared__ float red[2];
    int row = blockIdx.x;
    int t = threadIdx.x;
    float x = seqs[row * HH + t];
    float m = waveSum(x);
    if ((t & 63) == 0) red[t >> 6] = m;
    __syncthreads();
    m = (red[0] + red[1]) * (1.0f / HH);
    float d = x - m;
    __syncthreads();
    float v2 = waveSum(d * d);
    if ((t & 63) == 0) red[t >> 6] = v2;
    __syncthreads();
    float var = (red[0] + red[1]) * (1.0f / HH);
    float lf = d * rsqrtf(var + 1e-8f) * lnf_g[t] + lnf_b[t];
    int pid = pos_seqs[row];
    int nid = neg_seqs[row];
    float pp = lf * item_emb[pid * HH + t];
    float nn = lf * item_emb[nid * HH + t];
    __syncthreads();
    float ps = waveSum(pp);
    if ((t & 63) == 0) red[t >> 6] = ps;
    __syncthreads();
    float ptot = red[0] + red[1];
    __syncthreads();
    float ns = waveSum(nn);
    if ((t & 63) == 0) red[t >> 6] = ns;
    __syncthreads();
    float ntot = red[0] + red[1];
    if (t == 0) {
        out[row] = ptot;
        out[BB * LL + row] = ntot;
    }
}

extern "C" void kernel_launch(void* const* d_in, const int* in_sizes, int n_in,
                              void* d_out, int out_size, void* d_ws, size_t ws_size,
                              hipStream_t stream) {
    const int* log_seqs = (const int*)d_in[1];
    const int* tm       = (const int*)d_in[2];
    const int* pos_seqs = (const int*)d_in[3];
    const int* neg_seqs = (const int*)d_in[4];
    const float* item_emb = (const float*)d_in[5];
    const float* posK   = (const float*)d_in[6];
    const float* posV   = (const float*)d_in[7];
    const float* timeK  = (const float*)d_in[8];
    const float* timeV  = (const float*)d_in[9];
    const float* Wq = (const float*)d_in[10];
    const float* bq = (const float*)d_in[11];
    const float* Wk = (const float*)d_in[12];
    const float* bk = (const float*)d_in[13];
    const float* Wv = (const float*)d_in[14];
    const float* bv = (const float*)d_in[15];
    const float* ln1_g = (const float*)d_in[16];
    const float* ln1_b = (const float*)d_in[17];
    const float* W1 = (const float*)d_in[18];
    const float* b1 = (const float*)d_in[19];
    const float* W2 = (const float*)d_in[20];
    const float* b2 = (const float*)d_in[21];
    const float* ln2_g = (const float*)d_in[22];
    const float* ln2_b = (const float*)d_in[23];
    const float* lnf_g = (const float*)d_in[24];
    const float* lnf_b = (const float*)d_in[25];

    float* ws    = (float*)d_ws;
    float* seqs  = ws;                   // 409600
    float* Qb    = seqs + 409600;
    float* Kpb   = Qb + 409600;
    float* Vpb   = Kpb + 409600;
    float* AO    = Vpb + 409600;         // attn-out / ffn-delta
    float* projK = AO + 409600;          // 32*200*257 = 1,644,800

    k_embed<<<BB * LL, HH, 0, stream>>>(log_seqs, item_emb, seqs);
    for (int i = 0; i < 2; ++i) {
        k_qkv_t<<<BB * LL / 16, 256, 0, stream>>>(seqs,
            Wq + i * HH * HH, bq + i * HH,
            Wk + i * HH * HH, bk + i * HH,
            Wv + i * HH * HH, bv + i * HH,
            posK, posV, Qb, Kpb, Vpb);
        k_proj<<<32 * 7, 256, 0, stream>>>(Qb, timeK, projK);
        k_attn<<<32 * NQT, 256, 0, stream>>>(Qb, Kpb, Vpb, projK, timeV,
                                             tm, log_seqs, AO);
        k_add_ln<<<BB * LL, HH, 0, stream>>>(seqs, AO, ln1_g + i * HH, ln1_b + i * HH,
                                             log_seqs, 0);
        k_ffn_t<<<BB * LL / 16, 256, 0, stream>>>(seqs, W1 + i * HH * HH, b1 + i * HH,
                                                  W2 + i * HH * HH, b2 + i * HH, AO);
        k_add_ln<<<BB * LL, HH, 0, stream>>>(seqs, AO, ln2_g + i * HH, ln2_b + i * HH,
                                             log_seqs, 1);
    }
    k_final<<<BB * LL, HH, 0, stream>>>(seqs, lnf_g, lnf_b, item_emb,
                                        pos_seqs, neg_seqs, (float*)d_out);
}

// Round 3
// 236.067 us; speedup vs baseline: 2.1829x; 1.0805x over previous
//
#include <hip/hip_runtime.h>
#include <hip/hip_bf16.h>
#include <math.h>

#define BB 16
#define LL 200
#define HH 128
#define DD 64
#define QT2 8
#define NQT2 25         // 200/8 exact
#define NEGF -4294967295.0f
#define SQRTH 11.313708498984761f

__device__ __forceinline__ float waveSum(float v) {
    v += __shfl_xor(v, 1, 64);
    v += __shfl_xor(v, 2, 64);
    v += __shfl_xor(v, 4, 64);
    v += __shfl_xor(v, 8, 64);
    v += __shfl_xor(v, 16, 64);
    v += __shfl_xor(v, 32, 64);
    return v;
}

// ---------------- embed ----------------
__global__ void k_embed(const int* __restrict__ log_seqs,
                        const float* __restrict__ item_emb,
                        float* __restrict__ seqs) {
    int row = blockIdx.x;
    int t = threadIdx.x;
    int id = log_seqs[row];
    float v = (id == 0) ? 0.0f : item_emb[id * HH + t] * SQRTH;
    seqs[row * HH + t] = v;
}

// ---------------- QKV projection: 16 rows/block, 512 threads ----------------
__global__ __launch_bounds__(512) void k_qkv_t(const float* __restrict__ seqs,
    const float* __restrict__ Wq, const float* __restrict__ bq,
    const float* __restrict__ Wk, const float* __restrict__ bk,
    const float* __restrict__ Wv, const float* __restrict__ bv,
    const float* __restrict__ posK, const float* __restrict__ posV,
    float* __restrict__ Q, float* __restrict__ Kp, float* __restrict__ Vp) {
    __shared__ float s_lds[16][HH];
    int r0g = blockIdx.x * 16;
    int t = threadIdx.x;
    ((float4*)s_lds)[t] = ((const float4*)(seqs + r0g * HH))[t];
    __syncthreads();
    int c = t & 127, rg = t >> 7;
    float aq[4] = {0.f, 0.f, 0.f, 0.f};
    float ak[4] = {0.f, 0.f, 0.f, 0.f};
    float av[4] = {0.f, 0.f, 0.f, 0.f};
    const float4* wq4 = (const float4*)(Wq + c * HH);
    const float4* wk4 = (const float4*)(Wk + c * HH);
    const float4* wv4 = (const float4*)(Wv + c * HH);
#pragma unroll 4
    for (int k4 = 0; k4 < HH / 4; ++k4) {
        float4 wq = wq4[k4], wk = wk4[k4], wv = wv4[k4];
#pragma unroll
        for (int r = 0; r < 4; ++r) {
            float4 s = *(const float4*)&s_lds[rg * 4 + r][k4 * 4];
            aq[r] += s.x * wq.x + s.y * wq.y + s.z * wq.z + s.w * wq.w;
            ak[r] += s.x * wk.x + s.y * wk.y + s.z * wk.z + s.w * wk.w;
            av[r] += s.x * wv.x + s.y * wv.y + s.z * wv.z + s.w * wv.w;
        }
    }
#pragma unroll
    for (int r = 0; r < 4; ++r) {
        int row = r0g + rg * 4 + r;
        int l = row % LL;
        Q[row * HH + c]  = aq[r] + bq[c];
        Kp[row * HH + c] = ak[r] + bk[c] + posK[l * HH + c];
        Vp[row * HH + c] = av[r] + bv[c] + posV[l * HH + c];
    }
}

// ---------------- projK[b,h,q,tt] = Q[b,q,h,:] . timeK[tt,h,:] ----------------
// grid = 32 bh * 13 qtiles(16)
__global__ __launch_bounds__(256) void k_proj(const float* __restrict__ Q,
    const float* __restrict__ timeK, float* __restrict__ projK) {
    int bh = blockIdx.x / 13, qt = blockIdx.x % 13;
    int b = bh >> 1, h = bh & 1;
    int qlo = qt * 16;
    int qmax = LL - qlo; if (qmax > 16) qmax = 16;
    __shared__ float Qs[16][DD];
    int t = threadIdx.x;
    {
        int r = t >> 4, d4 = t & 15;
        float4 v = make_float4(0.f, 0.f, 0.f, 0.f);
        if (qlo + r < LL) v = ((const float4*)(Q + (b * LL + qlo + r) * HH + h * DD))[d4];
        *(float4*)&Qs[r][d4 * 4] = v;
    }
    __syncthreads();
    for (int tt = t; tt < 257; tt += 256) {
        float4 kr[16];
        const float4* tk4 = (const float4*)(timeK + tt * HH + h * DD);
#pragma unroll
        for (int d4 = 0; d4 < 16; ++d4) kr[d4] = tk4[d4];
        for (int r = 0; r < qmax; ++r) {
            float acc = 0.f;
#pragma unroll
            for (int d4 = 0; d4 < 16; ++d4) {
                float4 qv = *(const float4*)&Qs[r][d4 * 4];
                acc += qv.x * kr[d4].x + qv.y * kr[d4].y + qv.z * kr[d4].z + qv.w * kr[d4].w;
            }
            projK[(bh * LL + qlo + r) * 257 + tt] = acc;
        }
    }
}

// ---------------- fused scores + softmax + hist + PV ----------------
// grid = 32 bh * 25 qtiles(8); 256 threads: tq = t>>5 (q row), lane = t&31
__global__ __launch_bounds__(256) void k_attn(
    const float* __restrict__ Q, const float* __restrict__ Kp, const float* __restrict__ Vp,
    const float* __restrict__ projK, const float* __restrict__ timeV,
    const int* __restrict__ tm, const int* __restrict__ log_seqs,
    float* __restrict__ attnout) {
    int bh = blockIdx.x / NQT2, qt = blockIdx.x % NQT2;
    int b = bh >> 1, h = bh & 1;
    int qlo = qt * QT2;
    __shared__ float Qs[QT2][68];
    __shared__ float KV[64][68];
    __shared__ float S[QT2][212];
    __shared__ float hist[QT2][260];
    int t = threadIdx.x;
    int tq = t >> 5, lane = t & 31;
    int q = qlo + tq;                 // always < 200 (25*8 = 200)
    int qhi = qlo + QT2 - 1;

    if (t < QT2 * 16) {
        int r = t >> 4, d4 = t & 15;
        *(float4*)&Qs[r][d4 * 4] = ((const float4*)(Q + (b * LL + qlo + r) * HH + h * DD))[d4];
    }
    for (int x = t; x < QT2 * 212; x += 256) ((float*)S)[x] = NEGF;
    for (int x = t; x < QT2 * 260; x += 256) ((float*)hist)[x] = 0.f;
    __syncthreads();

    const int* tmrow = tm + (b * LL + q) * LL;
    const float* projrow = projK + (bh * LL + q) * 257;

    // phase 1: scores
    for (int kt = 0; kt * 64 <= qhi; ++kt) {
        int kbase = kt * 64;
        for (int x = t; x < 64 * 16; x += 256) {
            int i = x >> 4, d4 = x & 15;
            int k = kbase + i;
            if (k < LL)
                *(float4*)&KV[i][d4 * 4] =
                    ((const float4*)(Kp + (b * LL + k) * HH + h * DD))[d4];
        }
        __syncthreads();
#pragma unroll
        for (int j = 0; j < 2; ++j) {
            int kk = lane + 32 * j;
            int k = kbase + kk;
            if (k <= q && log_seqs[b * LL + k] != 0) {
                float acc = 0.f;
#pragma unroll
                for (int d4 = 0; d4 < 16; ++d4) {
                    float4 qv = *(const float4*)&Qs[tq][d4 * 4];
                    float4 kv = *(const float4*)&KV[kk][d4 * 4];
                    acc += qv.x * kv.x + qv.y * kv.y + qv.z * kv.z + qv.w * kv.w;
                }
                S[tq][k] = (acc + projrow[tmrow[k]]) * 0.125f;
            }
        }
        __syncthreads();
    }

    // phase 2: softmax (32 lanes per q row)
    float mx = -INFINITY;
    for (int k = lane; k < LL; k += 32) mx = fmaxf(mx, S[tq][k]);
    mx = fmaxf(mx, __shfl_xor(mx, 1, 64));
    mx = fmaxf(mx, __shfl_xor(mx, 2, 64));
    mx = fmaxf(mx, __shfl_xor(mx, 4, 64));
    mx = fmaxf(mx, __shfl_xor(mx, 8, 64));
    mx = fmaxf(mx, __shfl_xor(mx, 16, 64));
    bool allmask = (mx == NEGF);
    float sum = 0.f;
    for (int k = lane; k < LL; k += 32) {
        float e = __expf(S[tq][k] - mx);
        S[tq][k] = e;
        sum += e;
    }
    sum += __shfl_xor(sum, 1, 64);
    sum += __shfl_xor(sum, 2, 64);
    sum += __shfl_xor(sum, 4, 64);
    sum += __shfl_xor(sum, 8, 64);
    sum += __shfl_xor(sum, 16, 64);
    float inv = 1.0f / sum;
    for (int k = lane; k < LL; k += 32) S[tq][k] *= inv;

    int klim = allmask ? LL : (q + 1);
    // hist[tq][tt] = sum_k A[q,k] * [tm[q,k]==tt]  (LDS atomics, own-wave only)
    for (int k = lane; k < klim; k += 32)
        atomicAdd(&hist[tq][tmrow[k]], S[tq][k]);

    // phase 3: out = sum_k A*Vp[k]  +  sum_tt hist*timeV[tt]   (unified chunks)
    float2 acc = make_float2(0.f, 0.f);
    for (int c = 0; c < 9; ++c) {
        __syncthreads();
        int kend;
        const float* wrow;
        if (c < 4) {
            int kbase = c * 64;
            for (int x = t; x < 64 * 16; x += 256) {
                int i = x >> 4, d4 = x & 15;
                int k = kbase + i;
                if (k < LL)
                    *(float4*)&KV[i][d4 * 4] =
                        ((const float4*)(Vp + (b * LL + k) * HH + h * DD))[d4];
            }
            kend = klim - kbase; if (kend > 64) kend = 64;
            wrow = &S[tq][kbase];
        } else {
            int tb = (c - 4) * 64;
            for (int x = t; x < 64 * 16; x += 256) {
                int i = x >> 4, d4 = x & 15;
                int tt = tb + i;
                if (tt < 257)
                    *(float4*)&KV[i][d4 * 4] =
                        ((const float4*)(timeV + tt * HH + h * DD))[d4];
            }
            kend = 257 - tb; if (kend > 64) kend = 64;
            wrow = &hist[tq][tb];
        }
        __syncthreads();
#pragma unroll 4
        for (int i = 0; i < kend; ++i) {
            float w = wrow[i];
            float2 vv = *(const float2*)&KV[i][lane * 2];
            acc.x += w * vv.x;
            acc.y += w * vv.y;
        }
    }
    *(float2*)(attnout + (b * LL + q) * HH + h * DD + lane * 2) = acc;
}

// ---------------- fused: s1 = LN(seqs + AO); seqs = s1; delta = FFN(s1) ----------------
__global__ __launch_bounds__(512) void k_ffn_ln(
    float* __restrict__ seqs, const float* __restrict__ AO,
    const float* __restrict__ g1, const float* __restrict__ be1,
    const float* __restrict__ W1, const float* __restrict__ b1,
    const float* __restrict__ W2, const float* __restrict__ b2,
    float* __restrict__ delta) {
    __shared__ float s_lds[16][HH];
    __shared__ float h_lds[16][HH];
    int r0g = blockIdx.x * 16;
    int t = threadIdx.x;
    {
        float4 a = ((const float4*)(seqs + r0g * HH))[t];
        float4 o = ((const float4*)(AO + r0g * HH))[t];
        a.x += o.x; a.y += o.y; a.z += o.z; a.w += o.w;
        ((float4*)s_lds)[t] = a;
    }
    __syncthreads();
    // LayerNorm: wave w handles rows 2w, 2w+1 (32 lanes each)
    {
        int w = t >> 6, lane = t & 63;
        int row = w * 2 + (lane >> 5), cl = lane & 31;
        float sm = 0.f;
#pragma unroll
        for (int j = 0; j < 4; ++j) sm += s_lds[row][cl + 32 * j];
        sm += __shfl_xor(sm, 1, 64);
        sm += __shfl_xor(sm, 2, 64);
        sm += __shfl_xor(sm, 4, 64);
        sm += __shfl_xor(sm, 8, 64);
        sm += __shfl_xor(sm, 16, 64);
        float mean = sm * (1.0f / HH);
        float vr = 0.f;
#pragma unroll
        for (int j = 0; j < 4; ++j) {
            float d = s_lds[row][cl + 32 * j] - mean;
            vr += d * d;
        }
        vr += __shfl_xor(vr, 1, 64);
        vr += __shfl_xor(vr, 2, 64);
        vr += __shfl_xor(vr, 4, 64);
        vr += __shfl_xor(vr, 8, 64);
        vr += __shfl_xor(vr, 16, 64);
        float rstd = rsqrtf(vr * (1.0f / HH) + 1e-8f);
#pragma unroll
        for (int j = 0; j < 4; ++j) {
            int c = cl + 32 * j;
            s_lds[row][c] = (s_lds[row][c] - mean) * rstd * g1[c] + be1[c];
        }
    }
    __syncthreads();
    ((float4*)(seqs + r0g * HH))[t] = ((float4*)s_lds)[t];   // s1 out (residual for ln2)
    // FFN GEMM1 + relu
    int c = t & 127, rg = t >> 7;
    float acc[4] = {0.f, 0.f, 0.f, 0.f};
    const float4* w14 = (const float4*)(W1 + c * HH);
#pragma unroll 4
    for (int k4 = 0; k4 < HH / 4; ++k4) {
        float4 w = w14[k4];
#pragma unroll
        for (int r = 0; r < 4; ++r) {
            float4 s = *(const float4*)&s_lds[rg * 4 + r][k4 * 4];
            acc[r] += s.x * w.x + s.y * w.y + s.z * w.z + s.w * w.w;
        }
    }
#pragma unroll
    for (int r = 0; r < 4; ++r) h_lds[rg * 4 + r][c] = fmaxf(acc[r] + b1[c], 0.f);
    __syncthreads();
    // FFN GEMM2
#pragma unroll
    for (int r = 0; r < 4; ++r) acc[r] = 0.f;
    const float4* w24 = (const float4*)(W2 + c * HH);
#pragma unroll 4
    for (int k4 = 0; k4 < HH / 4; ++k4) {
        float4 w = w24[k4];
#pragma unroll
        for (int r = 0; r < 4; ++r) {
            float4 s = *(const float4*)&h_lds[rg * 4 + r][k4 * 4];
            acc[r] += s.x * w.x + s.y * w.y + s.z * w.z + s.w * w.w;
        }
    }
#pragma unroll
    for (int r = 0; r < 4; ++r)
        delta[(r0g + rg * 4 + r) * HH + c] = acc[r] + b2[c];
}

// ---------------- residual add + LayerNorm (+ keep mask) ----------------
__global__ void k_add_ln(float* __restrict__ seqs, const float* __restrict__ delta,
                         const float* __restrict__ g, const float* __restrict__ beta,
                         const int* __restrict__ log_seqs, int keep) {
    __shared__ float red[2];
    int row = blockIdx.x;
    int t = threadIdx.x;
    float x = seqs[row * HH + t] + delta[row * HH + t];
    float m = waveSum(x);
    if ((t & 63) == 0) red[t >> 6] = m;
    __syncthreads();
    m = (red[0] + red[1]) * (1.0f / HH);
    float d = x - m;
    __syncthreads();
    float v2 = waveSum(d * d);
    if ((t & 63) == 0) red[t >> 6] = v2;
    __syncthreads();
    float var = (red[0] + red[1]) * (1.0f / HH);
    float y = d * rsqrtf(var + 1e-8f) * g[t] + beta[t];
    if (keep && log_seqs[row] == 0) y = 0.f;
    seqs[row * HH + t] = y;
}

// ---------------- final LN + logits ----------------
__global__ void k_final(const float* __restrict__ seqs,
                        const float* __restrict__ lnf_g, const float* __restrict__ lnf_b,
                        const float* __restrict__ item_emb,
                        const int* __restrict__ pos_seqs, const int* __restrict__ neg_seqs,
                        float* __restrict__ out) {
    __shared__ float red[2];
    int row = blockIdx.x;
    int t = threadIdx.x;
    float x = seqs[row * HH + t];
    float m = waveSum(x);
    if ((t & 63) == 0) red[t >> 6] = m;
    __syncthreads();
    m = (red[0] + red[1]) * (1.0f / HH);
    float d = x - m;
    __syncthreads();
    float v2 = waveSum(d * d);
    if ((t & 63) == 0) red[t >> 6] = v2;
    __syncthreads();
    float var = (red[0] + red[1]) * (1.0f / HH);
    float lf = d * rsqrtf(var + 1e-8f) * lnf_g[t] + lnf_b[t];
    int pid = pos_seqs[row];
    int nid = neg_seqs[row];
    float pp = lf * item_emb[pid * HH + t];
    float nn = lf * item_emb[nid * HH + t];
    __syncthreads();
    float ps = waveSum(pp);
    if ((t & 63) == 0) red[t >> 6] = ps;
    __syncthreads();
    float ptot = red[0] + red[1];
    __syncthreads();
    float ns = waveSum(nn);
    if ((t & 63) == 0) red[t >> 6] = ns;
    __syncthreads();
    float ntot = red[0] + red[1];
    if (t == 0) {
        out[row] = ptot;
        out[BB * LL + row] = ntot;
    }
}

extern "C" void kernel_launch(void* const* d_in, const int* in_sizes, int n_in,
                              void* d_out, int out_size, void* d_ws, size_t ws_size,
                              hipStream_t stream) {
    const int* log_seqs = (const int*)d_in[1];
    const int* tm       = (const int*)d_in[2];
    const int* pos_seqs = (const int*)d_in[3];
    const int* neg_seqs = (const int*)d_in[4];
    const float* item_emb = (const float*)d_in[5];
    const float* posK   = (const float*)d_in[6];
    const float* posV   = (const float*)d_in[7];
    const float* timeK  = (const float*)d_in[8];
    const float* timeV  = (const float*)d_in[9];
    const float* Wq = (const float*)d_in[10];
    const float* bq = (const float*)d_in[11];
    const float* Wk = (const float*)d_in[12];
    const float* bk = (const float*)d_in[13];
    const float* Wv = (const float*)d_in[14];
    const float* bv = (const float*)d_in[15];
    const float* ln1_g = (const float*)d_in[16];
    const float* ln1_b = (const float*)d_in[17];
    const float* W1 = (const float*)d_in[18];
    const float* b1 = (const float*)d_in[19];
    const float* W2 = (const float*)d_in[20];
    const float* b2 = (const float*)d_in[21];
    const float* ln2_g = (const float*)d_in[22];
    const float* ln2_b = (const float*)d_in[23];
    const float* lnf_g = (const float*)d_in[24];
    const float* lnf_b = (const float*)d_in[25];

    float* ws    = (float*)d_ws;
    float* seqs  = ws;                   // 409600
    float* Qb    = seqs + 409600;
    float* Kpb   = Qb + 409600;
    float* Vpb   = Kpb + 409600;
    float* AO    = Vpb + 409600;         // attn-out / ffn-delta
    float* projK = AO + 409600;          // 32*200*257 = 1,644,800

    k_embed<<<BB * LL, HH, 0, stream>>>(log_seqs, item_emb, seqs);
    for (int i = 0; i < 2; ++i) {
        k_qkv_t<<<BB * LL / 16, 512, 0, stream>>>(seqs,
            Wq + i * HH * HH, bq + i * HH,
            Wk + i * HH * HH, bk + i * HH,
            Wv + i * HH * HH, bv + i * HH,
            posK, posV, Qb, Kpb, Vpb);
        k_proj<<<32 * 13, 256, 0, stream>>>(Qb, timeK, projK);
        k_attn<<<32 * NQT2, 256, 0, stream>>>(Qb, Kpb, Vpb, projK, timeV,
                                              tm, log_seqs, AO);
        k_ffn_ln<<<BB * LL / 16, 512, 0, stream>>>(seqs, AO,
            ln1_g + i * HH, ln1_b + i * HH,
            W1 + i * HH * HH, b1 + i * HH,
            W2 + i * HH * HH, b2 + i * HH, AO);
        k_add_ln<<<BB * LL, HH, 0, stream>>>(seqs, AO, ln2_g + i * HH, ln2_b + i * HH,
                                             log_seqs, 1);
    }
    k_final<<<BB * LL, HH, 0, stream>>>(seqs, lnf_g, lnf_b, item_emb,
                                        pos_seqs, neg_seqs, (float*)d_out);
}